// Round 3
// baseline (610.311 us; speedup 1.0000x reference)
//
#include <hip/hip_runtime.h>
#include <math.h>

#define K_DIM 2048
#define M_DIM 512
#define N_DIM 64
#define EPSF 1e-8f
#define ROWS 8
#define TPB 512

typedef float f32x4 __attribute__((ext_vector_type(4)));

// ---------------------------------------------------------------------------
// Kernel A: per-column n, thr = L-th largest of w_b[:,n]; write scores_hard.
// thr = min{ v in column : count(column > v) <= L-1 }  (duplicate-safe)
// ---------------------------------------------------------------------------
__global__ __launch_bounds__(256) void thr_hard_kernel(
    const float* __restrict__ w_b, const int* __restrict__ lptr,
    float* __restrict__ scores_hard) {
  __shared__ float col[M_DIM];
  __shared__ float red[256];
  const int n = blockIdx.x;   // 0..N-1
  const int t = threadIdx.x;  // 0..255
  const int L = lptr[0];

  col[t]       = w_b[t * N_DIM + n];
  col[t + 256] = w_b[(t + 256) * N_DIM + n];
  __syncthreads();

  const float v0 = col[t], v1 = col[t + 256];
  int c0 = 0, c1 = 0;
  for (int i = 0; i < M_DIM; ++i) {
    const float c = col[i];  // broadcast read, conflict-free
    c0 += (c > v0);
    c1 += (c > v1);
  }
  float cand0 = (c0 <= L - 1) ? v0 : INFINITY;
  float cand1 = (c1 <= L - 1) ? v1 : INFINITY;
  red[t] = fminf(cand0, cand1);
  __syncthreads();
  for (int s = 128; s > 0; s >>= 1) {
    if (t < s) red[t] = fminf(red[t], red[t + s]);
    __syncthreads();
  }
  const float thr = red[0];

  // scores_hard[m][n] = (clip(w_b - thr + EPS, -1, 1) + 1) * 0.5
  {
    float sh0 = (col[t] - thr) + EPSF;
    float sh1 = (col[t + 256] - thr) + EPSF;
    sh0 = fminf(fmaxf(sh0, -1.0f), 1.0f);
    sh1 = fminf(fmaxf(sh1, -1.0f), 1.0f);
    scores_hard[t * N_DIM + n]         = (sh0 + 1.0f) * 0.5f;
    scores_hard[(t + 256) * N_DIM + n] = (sh1 + 1.0f) * 0.5f;
  }
}

// ---------------------------------------------------------------------------
// Kernel B: fused GEMM (S = x @ w_att) -> row softmax -> write scores_soft.
// 256 blocks x 512 threads; block b owns k-rows [8b, 8b+8).
// (r2 GEMM layout: 4 rows x 2 cols/thread, 4 broadcast b128 LDS reads/step)
// ---------------------------------------------------------------------------
__global__ __launch_bounds__(TPB) void gemm_softmax_kernel(
    const float* __restrict__ x, const float* __restrict__ w,
    float* __restrict__ soft) {
  __shared__ float xs[ROWS][M_DIM];  // 16 KiB x tile
  __shared__ float sm[ROWS][M_DIM];  // 16 KiB soft rows
  const int t = threadIdx.x;         // 0..511
  const int k0 = blockIdx.x * ROWS;

  // ---- phase 1: stage x tile ----
  {
    const f32x4* xg = (const f32x4*)(x + (size_t)k0 * M_DIM);
    f32x4* xsv = (f32x4*)&xs[0][0];
    xsv[t]       = xg[t];
    xsv[t + TPB] = xg[t + TPB];
  }
  __syncthreads();

  // ---- phase 2: GEMM, 4 rows x 2 cols per thread ----
  {
    const int half = t >> 8;      // wave-uniform row-group (0/1)
    const int j0 = t & 255;       // first owned column
    const int r0 = half * 4;
    float acc[4][2];
#pragma unroll
    for (int r = 0; r < 4; ++r) { acc[r][0] = 0.0f; acc[r][1] = 0.0f; }

#pragma unroll 2
    for (int m = 0; m < M_DIM; m += 4) {
      float wa[4], wb[4];
#pragma unroll
      for (int i = 0; i < 4; ++i) {
        wa[i] = w[(m + i) * M_DIM + j0];
        wb[i] = w[(m + i) * M_DIM + j0 + 256];
      }
#pragma unroll
      for (int r = 0; r < 4; ++r) {
        const float4 xv = *(const float4*)&xs[r0 + r][m];  // broadcast b128
        acc[r][0] += xv.x * wa[0] + xv.y * wa[1] + xv.z * wa[2] + xv.w * wa[3];
        acc[r][1] += xv.x * wb[0] + xv.y * wb[1] + xv.z * wb[2] + xv.w * wb[3];
      }
    }
#pragma unroll
    for (int r = 0; r < 4; ++r) {
      sm[r0 + r][j0]       = acc[r][0];
      sm[r0 + r][j0 + 256] = acc[r][1];
    }
  }
  __syncthreads();

  // ---- phase 3: softmax, one row per wave; write soft ----
  {
    const int r = t >> 6, ln = t & 63;
    float v[8];
    float mx = -INFINITY;
#pragma unroll
    for (int i = 0; i < 8; ++i) {
      v[i] = sm[r][ln + 64 * i];
      mx = fmaxf(mx, v[i]);
    }
#pragma unroll
    for (int s = 32; s > 0; s >>= 1) mx = fmaxf(mx, __shfl_xor(mx, s));
    float sum = 0.0f;
#pragma unroll
    for (int i = 0; i < 8; ++i) {
      v[i] = expf(v[i] - mx);
      sum += v[i];
    }
#pragma unroll
    for (int s = 32; s > 0; s >>= 1) sum += __shfl_xor(sum, s);
    const float inv = 1.0f / sum;
    float* srow = soft + (size_t)(k0 + r) * M_DIM;
#pragma unroll
    for (int i = 0; i < 8; ++i) srow[ln + 64 * i] = v[i] * inv + EPSF;
  }
}

// ---------------------------------------------------------------------------
// Kernel C: combine, fill-like. 4096 blocks x 256 threads; block b owns the
// contiguous float4 range [4096b, 4096(b+1)) of BOTH out and mw (64 KiB each).
// Two single-stream store passes per block (out, then mw) — structurally
// identical to the poison fill that demonstrably hits 6.27 TB/s. All reads
// (soft 4 MB, x 4 MB, hard 128 KB) are L1/L2-resident broadcasts.
// ---------------------------------------------------------------------------
__global__ __launch_bounds__(256) void combine_kernel(
    const float* __restrict__ x, const float* __restrict__ hard,
    const float* __restrict__ soft, f32x4* __restrict__ out,
    f32x4* __restrict__ mw) {
  const int t = threadIdx.x;
  const int base = blockIdx.x * 4096;  // float4 index base
  const f32x4* hard4 = (const f32x4*)hard;

  // ---- pass 1: out ----
#pragma unroll 4
  for (int it = 0; it < 16; ++it) {
    const int g = base + it * 256 + t;
    const int pair = g >> 4;          // k*M + m
    const int q = g & 15;             // float4 index within n-row (= t&15)
    const int m = pair & (M_DIM - 1);
    const float ss = soft[pair];      // broadcast across 16 lanes
    const float xv = x[pair];
    const f32x4 sh = hard4[m * 16 + q];
    out[g] = sh * (ss * xv);
  }

  // ---- pass 2: mw (recompute — reads are cache-hot) ----
#pragma unroll 4
  for (int it = 0; it < 16; ++it) {
    const int g = base + it * 256 + t;
    const int pair = g >> 4;
    const int q = g & 15;
    const int m = pair & (M_DIM - 1);
    const float ss = soft[pair];
    const f32x4 sh = hard4[m * 16 + q];
    mw[g] = sh * ss;
  }
}

// ---------------------------------------------------------------------------
extern "C" void kernel_launch(void* const* d_in, const int* in_sizes, int n_in,
                              void* d_out, int out_size, void* d_ws,
                              size_t ws_size, hipStream_t stream) {
  const float* x     = (const float*)d_in[0];
  const float* w_att = (const float*)d_in[1];
  const float* w_b   = (const float*)d_in[2];
  const int*   lptr  = (const int*)d_in[3];

  float* out_base = (float*)d_out;
  const size_t OUT_SZ = (size_t)K_DIM * M_DIM * N_DIM;  // 67,108,864
  float* out0 = out_base;                               // out [K,M,N]
  float* hard = out0 + OUT_SZ;                          // scores_hard [M,N]
  float* soft = hard + (size_t)M_DIM * N_DIM;           // scores_soft [K,M]
  float* mwp  = soft + (size_t)K_DIM * M_DIM;           // mask_weight [K,M,N]

  thr_hard_kernel<<<N_DIM, 256, 0, stream>>>(w_b, lptr, hard);
  gemm_softmax_kernel<<<K_DIM / ROWS, TPB, 0, stream>>>(x, w_att, soft);

  const int total4 = K_DIM * M_DIM * (N_DIM / 4);  // 16,777,216 float4s
  combine_kernel<<<total4 / 4096, 256, 0, stream>>>(
      x, hard, soft, (f32x4*)out0, (f32x4*)mwp);
}

// Round 4
// 597.869 us; speedup vs baseline: 1.0208x; 1.0208x over previous
//
#include <hip/hip_runtime.h>
#include <math.h>

#define K_DIM 2048
#define M_DIM 512
#define N_DIM 64
#define EPSF 1e-8f
#define ROWS 8
#define TPB 512

typedef float f32x4 __attribute__((ext_vector_type(4)));

// ---------------------------------------------------------------------------
// Kernel A: per-column n, thr = L-th largest of w_b[:,n]; write scores_hard.
// thr = min{ v in column : count(column > v) <= L-1 }  (duplicate-safe)
// ---------------------------------------------------------------------------
__global__ __launch_bounds__(256) void thr_hard_kernel(
    const float* __restrict__ w_b, const int* __restrict__ lptr,
    float* __restrict__ scores_hard) {
  __shared__ float col[M_DIM];
  __shared__ float red[256];
  const int n = blockIdx.x;   // 0..N-1
  const int t = threadIdx.x;  // 0..255
  const int L = lptr[0];

  col[t]       = w_b[t * N_DIM + n];
  col[t + 256] = w_b[(t + 256) * N_DIM + n];
  __syncthreads();

  const float v0 = col[t], v1 = col[t + 256];
  int c0 = 0, c1 = 0;
  for (int i = 0; i < M_DIM; ++i) {
    const float c = col[i];  // broadcast read, conflict-free
    c0 += (c > v0);
    c1 += (c > v1);
  }
  float cand0 = (c0 <= L - 1) ? v0 : INFINITY;
  float cand1 = (c1 <= L - 1) ? v1 : INFINITY;
  red[t] = fminf(cand0, cand1);
  __syncthreads();
  for (int s = 128; s > 0; s >>= 1) {
    if (t < s) red[t] = fminf(red[t], red[t + s]);
    __syncthreads();
  }
  const float thr = red[0];

  // scores_hard[m][n] = (clip(w_b - thr + EPS, -1, 1) + 1) * 0.5
  {
    float sh0 = (col[t] - thr) + EPSF;
    float sh1 = (col[t + 256] - thr) + EPSF;
    sh0 = fminf(fmaxf(sh0, -1.0f), 1.0f);
    sh1 = fminf(fmaxf(sh1, -1.0f), 1.0f);
    scores_hard[t * N_DIM + n]         = (sh0 + 1.0f) * 0.5f;
    scores_hard[(t + 256) * N_DIM + n] = (sh1 + 1.0f) * 0.5f;
  }
}

// ---------------------------------------------------------------------------
// Kernel B: fused GEMM (S = x @ w_att) -> row softmax -> write scores_soft.
// 256 blocks x 512 threads; block b owns k-rows [8b, 8b+8).
// ---------------------------------------------------------------------------
__global__ __launch_bounds__(TPB) void gemm_softmax_kernel(
    const float* __restrict__ x, const float* __restrict__ w,
    float* __restrict__ soft) {
  __shared__ float xs[ROWS][M_DIM];  // 16 KiB x tile
  __shared__ float sm[ROWS][M_DIM];  // 16 KiB score rows
  const int t = threadIdx.x;         // 0..511
  const int k0 = blockIdx.x * ROWS;

  // ---- phase 1: stage x tile ----
  {
    const f32x4* xg = (const f32x4*)(x + (size_t)k0 * M_DIM);
    f32x4* xsv = (f32x4*)&xs[0][0];
    xsv[t]       = xg[t];
    xsv[t + TPB] = xg[t + TPB];
  }
  __syncthreads();

  // ---- phase 2: GEMM, 4 rows x 2 cols per thread ----
  {
    const int half = t >> 8;      // wave-uniform row-group (0/1)
    const int j0 = t & 255;       // first owned column
    const int r0 = half * 4;
    float acc[4][2];
#pragma unroll
    for (int r = 0; r < 4; ++r) { acc[r][0] = 0.0f; acc[r][1] = 0.0f; }

#pragma unroll 2
    for (int m = 0; m < M_DIM; m += 4) {
      float wa[4], wb[4];
#pragma unroll
      for (int i = 0; i < 4; ++i) {
        wa[i] = w[(m + i) * M_DIM + j0];
        wb[i] = w[(m + i) * M_DIM + j0 + 256];
      }
#pragma unroll
      for (int r = 0; r < 4; ++r) {
        const float4 xv = *(const float4*)&xs[r0 + r][m];  // broadcast b128
        acc[r][0] += xv.x * wa[0] + xv.y * wa[1] + xv.z * wa[2] + xv.w * wa[3];
        acc[r][1] += xv.x * wb[0] + xv.y * wb[1] + xv.z * wb[2] + xv.w * wb[3];
      }
    }
#pragma unroll
    for (int r = 0; r < 4; ++r) {
      sm[r0 + r][j0]       = acc[r][0];
      sm[r0 + r][j0 + 256] = acc[r][1];
    }
  }
  __syncthreads();

  // ---- phase 3: softmax, one row per wave; write soft ----
  {
    const int r = t >> 6, ln = t & 63;
    float v[8];
    float mx = -INFINITY;
#pragma unroll
    for (int i = 0; i < 8; ++i) {
      v[i] = sm[r][ln + 64 * i];
      mx = fmaxf(mx, v[i]);
    }
#pragma unroll
    for (int s = 32; s > 0; s >>= 1) mx = fmaxf(mx, __shfl_xor(mx, s));
    float sum = 0.0f;
#pragma unroll
    for (int i = 0; i < 8; ++i) {
      v[i] = expf(v[i] - mx);
      sum += v[i];
    }
#pragma unroll
    for (int s = 32; s > 0; s >>= 1) sum += __shfl_xor(sum, s);
    const float inv = 1.0f / sum;
    float* srow = soft + (size_t)(k0 + r) * M_DIM;
#pragma unroll
    for (int i = 0; i < 8; ++i) srow[ln + 64 * i] = v[i] * inv + EPSF;
  }
}

// ---------------------------------------------------------------------------
// Kernel C: combine with a LOAD-FREE streaming loop.
// Grid 2048 = (K/8) x (M/64) blocks of 256 threads. Block (kb, mt):
//   stage hard slice [m0, m0+64) -> LDS (16 KiB, once)
//   stage (ss, ss*xv) for its 8x64 (k,m) pairs -> LDS (4 KiB, once)
//   hot loop: ds_read_b64 (broadcast ab) + ds_read_b128 (sh) + 2 vec muls +
//             2 b128 stores. ZERO global loads -> VMEM queue = stores only,
//             structurally identical to the 6.27 TB/s poison fill.
// Per-wave stores are 1 KiB contiguous full lines.
// ---------------------------------------------------------------------------
__global__ __launch_bounds__(256) void combine_kernel(
    const float* __restrict__ x, const float* __restrict__ hard,
    const float* __restrict__ soft, f32x4* __restrict__ out,
    f32x4* __restrict__ mw) {
  __shared__ f32x4 sh_s[64 * 16];   // 16 KiB: hard[m0+mrel][4q..4q+4)
  __shared__ float2 ab_s[512];      // 4 KiB: (ss, ss*xv) per (krel, mrel)
  const int t = threadIdx.x;
  const int kb = blockIdx.x >> 3;   // 0..255
  const int mt = blockIdx.x & 7;    // 0..7
  const int k0 = kb * 8;
  const int m0 = mt * 64;
  const f32x4* hard4 = (const f32x4*)hard;

  // ---- stage hard slice (coalesced, L2-resident) ----
#pragma unroll
  for (int i = 0; i < 4; ++i) {
    const int idx = i * 256 + t;              // 0..1023
    sh_s[idx] = hard4[(m0 + (idx >> 4)) * 16 + (idx & 15)];
  }
  // ---- stage ab pairs ----
#pragma unroll
  for (int i = 0; i < 2; ++i) {
    const int p = i * 256 + t;                // krel*64 + mrel
    const int krel = p >> 6, mrel = p & 63;
    const size_t sidx = (size_t)(k0 + krel) * M_DIM + (m0 + mrel);
    const float ss = soft[sidx];
    const float xv = x[sidx];
    ab_s[p] = make_float2(ss, ss * xv);
  }
  __syncthreads();

  // ---- load-free streaming loop: 32 iterations, 2 KiB stored/wave/iter ----
  const int q = t & 15;
  const int grp = t >> 4;  // 0..15
#pragma unroll 4
  for (int it = 0; it < 32; ++it) {
    const int p = it * 16 + grp;              // pair index: krel*64 + mrel
    const int mrel = p & 63, krel = p >> 6;
    const f32x4 sh = sh_s[mrel * 16 + q];     // conflict-free b128
    const float2 ab = ab_s[p];                // 16-lane broadcast b64
    const f32x4 w4 = sh * ab.x;               // mask_weight chunk
    const f32x4 o4 = sh * ab.y;               // out chunk (independent of w4)
    const size_t g =
        ((size_t)(k0 + krel) * M_DIM + (m0 + mrel)) * 16 + q;
    out[g] = o4;
    mw[g]  = w4;
  }
}

// ---------------------------------------------------------------------------
extern "C" void kernel_launch(void* const* d_in, const int* in_sizes, int n_in,
                              void* d_out, int out_size, void* d_ws,
                              size_t ws_size, hipStream_t stream) {
  const float* x     = (const float*)d_in[0];
  const float* w_att = (const float*)d_in[1];
  const float* w_b   = (const float*)d_in[2];
  const int*   lptr  = (const int*)d_in[3];

  float* out_base = (float*)d_out;
  const size_t OUT_SZ = (size_t)K_DIM * M_DIM * N_DIM;  // 67,108,864
  float* out0 = out_base;                               // out [K,M,N]
  float* hard = out0 + OUT_SZ;                          // scores_hard [M,N]
  float* soft = hard + (size_t)M_DIM * N_DIM;           // scores_soft [K,M]
  float* mwp  = soft + (size_t)K_DIM * M_DIM;           // mask_weight [K,M,N]

  thr_hard_kernel<<<N_DIM, 256, 0, stream>>>(w_b, lptr, hard);
  gemm_softmax_kernel<<<K_DIM / ROWS, TPB, 0, stream>>>(x, w_att, soft);

  const int nblocks = (K_DIM / 8) * (M_DIM / 64);  // 2048
  combine_kernel<<<nblocks, 256, 0, stream>>>(
      x, hard, soft, (f32x4*)out0, (f32x4*)mwp);
}

// Round 5
// 596.320 us; speedup vs baseline: 1.0235x; 1.0026x over previous
//
#include <hip/hip_runtime.h>
#include <math.h>

#define K_DIM 2048
#define M_DIM 512
#define N_DIM 64
#define EPSF 1e-8f
#define ROWS 8
#define TPB 512

typedef float f32x4 __attribute__((ext_vector_type(4)));

// ---------------------------------------------------------------------------
// Kernel A: per-column n, thr = L-th largest of w_b[:,n]; write scores_hard.
// thr = min{ v in column : count(column > v) <= L-1 }  (duplicate-safe)
// ---------------------------------------------------------------------------
__global__ __launch_bounds__(256) void thr_hard_kernel(
    const float* __restrict__ w_b, const int* __restrict__ lptr,
    float* __restrict__ scores_hard) {
  __shared__ float col[M_DIM];
  __shared__ float red[256];
  const int n = blockIdx.x;   // 0..N-1
  const int t = threadIdx.x;  // 0..255
  const int L = lptr[0];

  col[t]       = w_b[t * N_DIM + n];
  col[t + 256] = w_b[(t + 256) * N_DIM + n];
  __syncthreads();

  const float v0 = col[t], v1 = col[t + 256];
  int c0 = 0, c1 = 0;
  for (int i = 0; i < M_DIM; ++i) {
    const float c = col[i];  // broadcast read, conflict-free
    c0 += (c > v0);
    c1 += (c > v1);
  }
  float cand0 = (c0 <= L - 1) ? v0 : INFINITY;
  float cand1 = (c1 <= L - 1) ? v1 : INFINITY;
  red[t] = fminf(cand0, cand1);
  __syncthreads();
  for (int s = 128; s > 0; s >>= 1) {
    if (t < s) red[t] = fminf(red[t], red[t + s]);
    __syncthreads();
  }
  const float thr = red[0];

  // scores_hard[m][n] = (clip(w_b - thr + EPS, -1, 1) + 1) * 0.5
  {
    float sh0 = (col[t] - thr) + EPSF;
    float sh1 = (col[t + 256] - thr) + EPSF;
    sh0 = fminf(fmaxf(sh0, -1.0f), 1.0f);
    sh1 = fminf(fmaxf(sh1, -1.0f), 1.0f);
    scores_hard[t * N_DIM + n]         = (sh0 + 1.0f) * 0.5f;
    scores_hard[(t + 256) * N_DIM + n] = (sh1 + 1.0f) * 0.5f;
  }
}

// ---------------------------------------------------------------------------
// Fused kernel v3: GEMM -> softmax -> two MONOTONE combine passes.
// 256 blocks x 512 threads; block b owns k-rows [8b, 8b+8).
// GEMM: 4 row-groups x 128 threads, each thread 2 rows x 4 consecutive cols:
//   float4 w loads (1 KiB/wave coalesced), 2 broadcast LDS b128 per m-step.
// Combine: pass 1 writes the block's FULL 1 MiB out slice monotone, pass 2
//   the 1 MiB mw slice — never interleaving the two streams. Their bases
//   differ by 0x10420000 (low 17 bits equal -> same channel+bank, different
//   DRAM row); 2 KiB-grain interleave ping-pongs the row buffer (suspected
//   2.5x write-BW penalty in r0-r4). Monotone passes eliminate it.
// ---------------------------------------------------------------------------
__global__ __launch_bounds__(TPB) void fused_kernel(
    const float* __restrict__ x, const float* __restrict__ w,
    const float* __restrict__ hard, float* __restrict__ soft,
    f32x4* __restrict__ out, f32x4* __restrict__ mw) {
  __shared__ float xs[ROWS][M_DIM];  // 16 KiB x tile
  __shared__ float sm[ROWS][M_DIM];  // 16 KiB score rows
  const int t = threadIdx.x;         // 0..511
  const int k0 = blockIdx.x * ROWS;

  // ---- phase 1: stage x tile ----
  {
    const f32x4* xg = (const f32x4*)(x + (size_t)k0 * M_DIM);
    f32x4* xsv = (f32x4*)&xs[0][0];
    xsv[t]       = xg[t];
    xsv[t + TPB] = xg[t + TPB];
  }
  __syncthreads();

  // ---- phase 2: GEMM, 2 rows x 4 consecutive cols per thread ----
  {
    const int grp = t >> 7;        // wave-pair-uniform row-group (0..3)
    const int c = t & 127;         // column quad index
    const int j0 = c * 4;          // first owned column
    const int r0 = grp * 2;
    f32x4 acc0 = {0.f, 0.f, 0.f, 0.f};
    f32x4 acc1 = {0.f, 0.f, 0.f, 0.f};

#pragma unroll 2
    for (int m = 0; m < M_DIM; m += 4) {
      f32x4 wv0 = *(const f32x4*)&w[(m + 0) * M_DIM + j0];
      f32x4 wv1 = *(const f32x4*)&w[(m + 1) * M_DIM + j0];
      f32x4 wv2 = *(const f32x4*)&w[(m + 2) * M_DIM + j0];
      f32x4 wv3 = *(const f32x4*)&w[(m + 3) * M_DIM + j0];
      const float4 xa = *(const float4*)&xs[r0 + 0][m];  // broadcast b128
      const float4 xb = *(const float4*)&xs[r0 + 1][m];  // broadcast b128
      acc0 += wv0 * xa.x + wv1 * xa.y + wv2 * xa.z + wv3 * xa.w;
      acc1 += wv0 * xb.x + wv1 * xb.y + wv2 * xb.z + wv3 * xb.w;
    }
    *(f32x4*)&sm[r0 + 0][j0] = acc0;  // b128 LDS write, conflict-free
    *(f32x4*)&sm[r0 + 1][j0] = acc1;
  }
  __syncthreads();

  // ---- phase 3: softmax, one row per wave ----
  {
    const int r = t >> 6, ln = t & 63;
    float v[8];
    float mx = -INFINITY;
#pragma unroll
    for (int i = 0; i < 8; ++i) {
      v[i] = sm[r][ln + 64 * i];
      mx = fmaxf(mx, v[i]);
    }
#pragma unroll
    for (int s = 32; s > 0; s >>= 1) mx = fmaxf(mx, __shfl_xor(mx, s));
    float sum = 0.0f;
#pragma unroll
    for (int i = 0; i < 8; ++i) {
      v[i] = expf(v[i] - mx);
      sum += v[i];
    }
#pragma unroll
    for (int s = 32; s > 0; s >>= 1) sum += __shfl_xor(sum, s);
    const float inv = 1.0f / sum;
#pragma unroll
    for (int i = 0; i < 8; ++i) sm[r][ln + 64 * i] = v[i] * inv + EPSF;
  }
  __syncthreads();

  // ---- phase 4a: write scores_soft ----
  {
    const f32x4* smv = (const f32x4*)&sm[0][0];
    f32x4* sg = (f32x4*)(soft + (size_t)k0 * M_DIM);
    sg[t]       = smv[t];
    sg[t + TPB] = smv[t + TPB];
  }

  // ---- phase 4b: combine pass 1 — out slice, 1 MiB monotone ----
  const f32x4* hard4 = (const f32x4*)hard;
  const size_t base = (size_t)k0 * (M_DIM * (N_DIM / 4));
#pragma unroll 8
  for (int it = 0; it < (ROWS * M_DIM * 16) / TPB; ++it) {
    const int g = it * TPB + t;
    const int q = g & 15;
    const int pm = g >> 4;             // r*512 + m
    const int m = pm & (M_DIM - 1);
    const int r = pm >> 9;
    const float ss = sm[r][m];         // LDS broadcast
    const float xv = xs[r][m];
    const f32x4 sh = hard4[m * 16 + q];  // L1-hot, 1 KiB/wave coalesced
    out[base + g] = sh * (ss * xv);
  }

  // ---- phase 4c: combine pass 2 — mw slice, 1 MiB monotone ----
#pragma unroll 8
  for (int it = 0; it < (ROWS * M_DIM * 16) / TPB; ++it) {
    const int g = it * TPB + t;
    const int q = g & 15;
    const int pm = g >> 4;
    const int m = pm & (M_DIM - 1);
    const int r = pm >> 9;
    const float ss = sm[r][m];
    const f32x4 sh = hard4[m * 16 + q];
    mw[base + g] = sh * ss;
  }
}

// ---------------------------------------------------------------------------
extern "C" void kernel_launch(void* const* d_in, const int* in_sizes, int n_in,
                              void* d_out, int out_size, void* d_ws,
                              size_t ws_size, hipStream_t stream) {
  const float* x     = (const float*)d_in[0];
  const float* w_att = (const float*)d_in[1];
  const float* w_b   = (const float*)d_in[2];
  const int*   lptr  = (const int*)d_in[3];

  float* out_base = (float*)d_out;
  const size_t OUT_SZ = (size_t)K_DIM * M_DIM * N_DIM;  // 67,108,864
  float* out0 = out_base;                               // out [K,M,N]
  float* hard = out0 + OUT_SZ;                          // scores_hard [M,N]
  float* soft = hard + (size_t)M_DIM * N_DIM;           // scores_soft [K,M]
  float* mwp  = soft + (size_t)K_DIM * M_DIM;           // mask_weight [K,M,N]

  thr_hard_kernel<<<N_DIM, 256, 0, stream>>>(w_b, lptr, hard);
  fused_kernel<<<K_DIM / ROWS, TPB, 0, stream>>>(
      x, w_att, hard, soft, (f32x4*)out0, (f32x4*)mwp);
}